// Round 17
// baseline (464.458 us; speedup 1.0000x reference)
//
#include <hip/hip_runtime.h>
#include <hip/hip_fp16.h>

#define NE 200000
#define NT 6250
#define NT64 3125
#define GRAM_BLOCKS 512

// ---- small device-global state only --------------------------------------
__device__ float g_st[21248];
__device__ unsigned short g_c4h[1024];  // C4 transposed [f][d], fp16
__device__ int g_flag64;

#define SUM1 (&g_st[0])
#define SQ1  (&g_st[256])
#define SUM2 (&g_st[512])
#define SQ2  (&g_st[768])
#define SUM3 (&g_st[1024])
#define SQ3  (&g_st[1152])
#define GMAT (&g_st[1280])
#define CS3  (&g_st[17664])
#define A1   (&g_st[17792])
#define C1   (&g_st[18048])
#define A2   (&g_st[18304])
#define C2   (&g_st[18560])
#define A3   (&g_st[18816])
#define C3   (&g_st[18944])
#define A4   (&g_st[19072])
#define C4   (&g_st[20096])

typedef unsigned short u16;
typedef _Float16 f16x8 __attribute__((ext_vector_type(8)));
typedef float f32x4 __attribute__((ext_vector_type(4)));

__device__ __forceinline__ f32x4 mfma16(f16x8 a, f16x8 b, f32x4 c) {
  return __builtin_amdgcn_mfma_f32_16x16x32_f16(a, b, c, 0, 0, 0);
}
__device__ __forceinline__ u16 f2h(float x) {
  __half h = __float2half_rn(x);
  return *reinterpret_cast<u16*>(&h);
}
__device__ __forceinline__ float h2f(u16 s) {
  __half h = *reinterpret_cast<__half*>(&s);
  return __half2float(h);
}
__device__ __forceinline__ float relu_np(float t) { return (t < 0.f) ? 0.f : t; }
__device__ __forceinline__ unsigned packh2(float a, float b) {
  return (unsigned)f2h(a) | ((unsigned)f2h(b) << 16);
}

// bad-path fill — keeps the template's expected kernel symbol
__global__ void GraphConv2_16518444221042_kernel(float* __restrict__ out,
                                                 float v, int n) {
  int i = blockIdx.x * 256 + threadIdx.x;
  if (i < n) out[i] = v;
}

// zero stats + edge_index dtype probe (merged)
__global__ void k_init(const int* __restrict__ e) {
  int i = blockIdx.x * 256 + threadIdx.x;
  if (i < 17792) g_st[i] = 0.f;
  if (i == 0) {
    int allz = 1;
    for (int k = 1; k < 128; k += 2) allz &= (e[k] == 0);
    g_flag64 = allz;
  }
}

// ---- pack W1/W2/W3 -> fp16 k-contiguous into d_out scratch -----------------
__global__ void k_packA(const float* __restrict__ W1,
                        const float* __restrict__ W2,
                        const float* __restrict__ W3,
                        u16* __restrict__ dst) {
  int i = blockIdx.x * 256 + threadIdx.x;
  if (i >= 163840) return;
  float v;
  if (i < 65536) {
    int n = i >> 8, k = i & 255;
    v = W1[k * 256 + n];
  } else if (i < 131072) {
    int i2 = i - 65536, n = i2 >> 8, k = i2 & 255;
    v = W2[k * 256 + n];
  } else {
    int i2 = i - 131072, n = i2 >> 8, k = i2 & 255;
    v = W3[k * 128 + n];
  }
  dst[i] = f2h(v);
}

// ---- pack W4/Wih/Whh into the DEAD y2 region of d_ws (after gemm3) ---------
__global__ void k_packB(const float* __restrict__ W4,
                        const float* __restrict__ Wih,
                        const float* __restrict__ Whh,
                        u16* __restrict__ dst) {
  int i = blockIdx.x * 256 + threadIdx.x;
  if (i >= 137216) return;
  float v;
  if (i < 131072) {
    int n = i >> 7, k = i & 127;
    v = W4[(size_t)k * 1024 + n];
  } else if (i < 134144) {
    v = Wih[i - 131072];
  } else {
    v = Whh[i - 134144];
  }
  dst[i] = f2h(v);
}

__global__ void k_finalize(const float* __restrict__ g,
                           const float* __restrict__ b, int which, int C) {
  int j = threadIdx.x;
  if (j < C) {
    const float* sum = (which == 1) ? SUM1 : (which == 2) ? SUM2 : SUM3;
    const float* sq  = (which == 1) ? SQ1 : (which == 2) ? SQ2 : SQ3;
    float* aa = (which == 1) ? A1 : (which == 2) ? A2 : A3;
    float* cc = (which == 1) ? C1 : (which == 2) ? C2 : C3;
    const float invE = 1.f / (float)NE;
    float mu = sum[j] * invE;
    float var = fmaf(-mu, mu, sq[j] * invE);
    float s = rsqrtf(var + 1e-5f);
    float av = g[j] * s;
    aa[j] = av;
    cc[j] = fmaf(-av, mu, b[j]);
  }
}

__global__ __launch_bounds__(64) void k_finalize4(
    const float* __restrict__ W4, const float* __restrict__ g4,
    const float* __restrict__ b4) {
  __shared__ float wsh[128];
  const int lane = threadIdx.x;
  const float invE = 1.f / (float)NE;
  for (int j = blockIdx.x; j < 1024; j += gridDim.x) {
    float w0 = W4[lane * 1024 + j];
    float w1 = W4[(lane + 64) * 1024 + j];
    wsh[lane] = w0;
    wsh[lane + 64] = w1;
    __syncthreads();
    float s0 = 0.f, s1 = 0.f;
#pragma unroll 8
    for (int k = 0; k < 128; ++k) {
      float wk = wsh[k];
      s0 = fmaf(GMAT[lane * 128 + k], wk, s0);
      s1 = fmaf(GMAT[(lane + 64) * 128 + k], wk, s1);
    }
    float acc = w0 * s0 + w1 * s1;
    float mac = CS3[lane] * w0 + CS3[lane + 64] * w1;
#pragma unroll
    for (int off = 32; off > 0; off >>= 1) {
      acc += __shfl_down(acc, off);
      mac += __shfl_down(mac, off);
    }
    if (lane == 0) {
      float mu = mac * invE;
      float var = fmaf(-mu, mu, acc * invE);
      float s = rsqrtf(var + 1e-5f);
      float av = g4[j] * s;
      A4[j] = av;
      float cv = fmaf(-av, mu, b4[j]);
      C4[j] = cv;
      g_c4h[(j & 31) * 32 + (j >> 5)] = f2h(cv);
    }
    __syncthreads();
  }
}

// ===== persistent MFMA GEMM: register-resident weights, 64-row tiles ========
template <int L>
__global__ __launch_bounds__(512) void k_gemmP(
    const float* __restrict__ node, const int* __restrict__ eidx,
    const u16* __restrict__ Yin, const u16* __restrict__ Wt,
    u16* __restrict__ Yout) {
  constexpr int CN = (L == 3) ? 128 : 256;
  constexpr int CTW = CN / 128;
  constexpr int LDH = 264;
  __shared__ __align__(16) u16 H[64 * LDH];
  __shared__ float csum_s[CN], csq_s[CN];
  __shared__ int idx_s[128];
  const int tid = threadIdx.x;
  float* SUMo = (L == 1) ? SUM1 : (L == 2) ? SUM2 : SUM3;
  float* SQo  = (L == 1) ? SQ1 : (L == 2) ? SQ2 : SQ3;
  const float* Ain = (L == 2) ? A1 : A2;
  const float* Cin = (L == 2) ? C1 : C2;

  const int l = tid & 63, w = tid >> 6;
  const int lr = l & 15, lg = l >> 4;

  f16x8 bfr[CTW][8];
#pragma unroll
  for (int c = 0; c < CTW; ++c)
#pragma unroll
    for (int kb = 0; kb < 8; ++kb)
      bfr[c][kb] = *(const f16x8*)&Wt[(size_t)((w * CTW + c) * 16 + lr) * 256 +
                                      kb * 32 + lg * 8];

  if (tid < CN) { csum_s[tid] = 0.f; csq_s[tid] = 0.f; }
  float sreg[CTW] = {}, qreg[CTW] = {};

  for (int t = blockIdx.x; t < NT64; t += gridDim.x) {
    const int r0 = t * 64;
    __syncthreads();
    if constexpr (L == 1) {
      if (tid < 128) {
        const int is64 = g_flag64;
        int m = tid & 63, sel = tid >> 6;
        int j = (r0 + m) * 2 + sel;
        int v = is64 ? eidx[j * 2] : eidx[j];
        v = v < 0 ? 0 : (v > 99999 ? 99999 : v);
        idx_s[sel * 64 + m] = v;
      }
      __syncthreads();
#pragma unroll
      for (int i = 0; i < 8; ++i) {
        int idx = tid + i * 512;
        int row = idx >> 6, col = (idx & 63) * 4;
        int sel = col >> 7, kc = col & 127;
        float4 v =
            *(const float4*)&node[(size_t)idx_s[sel * 64 + row] * 128 + kc];
        uint2 pk;
        pk.x = packh2(v.x, v.y);
        pk.y = packh2(v.z, v.w);
        *(uint2*)&H[row * LDH + col] = pk;
      }
    } else {
#pragma unroll
      for (int i = 0; i < 4; ++i) {
        int idx = tid + i * 512;
        int row = idx >> 5, col = (idx & 31) * 8;
        uint4 ld = *(const uint4*)&Yin[(size_t)(r0 + row) * 256 + col];
        const u16* sp = (const u16*)&ld;
        uint4 o;
        unsigned po[4];
#pragma unroll
        for (int p = 0; p < 4; ++p) {
          float v0 = relu_np(fmaf(Ain[col + 2 * p], h2f(sp[2 * p]),
                                  Cin[col + 2 * p]));
          float v1 = relu_np(fmaf(Ain[col + 2 * p + 1], h2f(sp[2 * p + 1]),
                                  Cin[col + 2 * p + 1]));
          po[p] = packh2(v0, v1);
        }
        o.x = po[0]; o.y = po[1]; o.z = po[2]; o.w = po[3];
        *(uint4*)&H[row * LDH + col] = o;
      }
    }
    __syncthreads();

    f32x4 acc[4][CTW] = {};
#pragma unroll
    for (int kb = 0; kb < 8; ++kb) {
      f16x8 a[4];
#pragma unroll
      for (int rt = 0; rt < 4; ++rt)
        a[rt] = *(const f16x8*)&H[(rt * 16 + lr) * LDH + kb * 32 + lg * 8];
#pragma unroll
      for (int c = 0; c < CTW; ++c)
#pragma unroll
        for (int rt = 0; rt < 4; ++rt)
          acc[rt][c] = mfma16(a[rt], bfr[c][kb], acc[rt][c]);
    }

#pragma unroll
    for (int c = 0; c < CTW; ++c) {
      const int col = (w * CTW + c) * 16 + lr;
#pragma unroll
      for (int rt = 0; rt < 4; ++rt)
#pragma unroll
        for (int r = 0; r < 4; ++r) {
          float v = acc[rt][c][r];
          sreg[c] += v;
          qreg[c] = fmaf(v, v, qreg[c]);
          int row = rt * 16 + lg * 4 + r;
          Yout[(size_t)(r0 + row) * CN + col] = f2h(v);
        }
    }
  }

  __syncthreads();
#pragma unroll
  for (int c = 0; c < CTW; ++c) {
    const int col = (w * CTW + c) * 16 + lr;
    atomicAdd(&csum_s[col], sreg[c]);
    atomicAdd(&csq_s[col], qreg[c]);
  }
  __syncthreads();
  if (tid < CN) {
    atomicAdd(&SUMo[tid], csum_s[tid]);
    atomicAdd(&SQo[tid], csq_s[tid]);
  }
}

// ===== MFMA Gram: coalesced loads, shared frag pool, atomic-free ===========
__global__ __launch_bounds__(256, 2) void k_gram_m(const u16* __restrict__ y3g,
                                                   float* __restrict__ pg) {
  __shared__ u16 h3T[128 * 40];  // transposed [col][row^swz]
  __shared__ float cred[128];
  const int tid = threadIdx.x;
  const int l = tid & 63, w = tid >> 6;
  const int lr = l & 15, lg = l >> 4;
  const int c4 = (tid & 31) * 4;
  const int rb = tid >> 5;
  f32x4 acc[2][8] = {};
  float csc[4] = {0.f, 0.f, 0.f, 0.f};

  for (int t = blockIdx.x; t < NT; t += gridDim.x) {
    const size_t r0 = (size_t)t * 32;
    __syncthreads();
#pragma unroll
    for (int i = 0; i < 4; ++i) {
      int row = rb + i * 8;
      ushort4 v = *(const ushort4*)&y3g[(r0 + row) * 128 + c4];
      float h[4];
      h[0] = relu_np(fmaf(A3[c4 + 0], h2f(v.x), C3[c4 + 0]));
      h[1] = relu_np(fmaf(A3[c4 + 1], h2f(v.y), C3[c4 + 1]));
      h[2] = relu_np(fmaf(A3[c4 + 2], h2f(v.z), C3[c4 + 2]));
      h[3] = relu_np(fmaf(A3[c4 + 3], h2f(v.w), C3[c4 + 3]));
#pragma unroll
      for (int j = 0; j < 4; ++j) {
        csc[j] += h[j];
        int col = c4 + j;
        int swz = ((col >> 2) & 3) << 3;
        h3T[col * 40 + (row ^ swz)] = f2h(h[j]);
      }
    }
    __syncthreads();
    f16x8 bfr[8];
#pragma unroll
    for (int tj = 0; tj < 8; ++tj) {
      int col = tj * 16 + lr;
      int swz = ((col >> 2) & 3) << 3;
      bfr[tj] = *(const f16x8*)&h3T[col * 40 + ((lg * 8) ^ swz)];
    }
#pragma unroll
    for (int ri = 0; ri < 2; ++ri) {
      f16x8 a = bfr[w * 2 + ri];
#pragma unroll
      for (int tj = 0; tj < 8; ++tj)
        acc[ri][tj] = mfma16(a, bfr[tj], acc[ri][tj]);
    }
  }
  float* my = pg + (size_t)blockIdx.x * 16384;
#pragma unroll
  for (int ri = 0; ri < 2; ++ri)
#pragma unroll
    for (int tj = 0; tj < 8; ++tj)
#pragma unroll
      for (int r = 0; r < 4; ++r) {
        int row = (w * 2 + ri) * 16 + lg * 4 + r, col = tj * 16 + lr;
        my[row * 128 + col] = acc[ri][tj][r];
      }
  if (tid < 128) cred[tid] = 0.f;
  __syncthreads();
#pragma unroll
  for (int j = 0; j < 4; ++j) atomicAdd(&cred[c4 + j], csc[j]);
  __syncthreads();
  if (tid < 128) atomicAdd(&CS3[tid], cred[tid]);
}

__global__ void k_gramred(const float* __restrict__ pg) {
  int g = blockIdx.x * 256 + threadIdx.x;
  float s = 0.f;
  for (int p = 0; p < GRAM_BLOCKS; ++p) s += pg[(size_t)p * 16384 + g];
  GMAT[g] = s;
}

// ==== final v3: 64-edge tiles, 64-col W4 slabs (32 barriers), 40 KB LDS =====
__global__ __launch_bounds__(256, 4) void k_final64(
    const u16* __restrict__ y3g, const u16* __restrict__ w4t,
    const u16* __restrict__ wihh, const u16* __restrict__ whhh,
    const float* __restrict__ edge, const float* __restrict__ hidden,
    const float* __restrict__ bias, const float* __restrict__ bih,
    const float* __restrict__ bhh, float* __restrict__ out) {
  __shared__ __align__(16) u16 H3[64 * 136];    // 17.4 KB
  __shared__ __align__(16) u16 SLAB[64 * 136];  // 17.4 KB (64 W4 cols)
  __shared__ __align__(16) u16 EDS[64 * 40];    // 5.1 KB
  float* OUTBUF = (float*)H3;   // [0, 8 KB) of H3 — dead after af hoist
  u16* MSGu = H3 + 4096;        // [8 KB, 13.1 KB) of H3
  const int tid = threadIdx.x;
  const size_t r0 = (size_t)blockIdx.x * 64;  // NE % 64 == 0: no tail

#pragma unroll
  for (int i = 0; i < 8; ++i) {  // H3 = relu(a3*y3+c3)
    int idx = tid + i * 256;
    int row = idx >> 5, col = (idx & 31) * 4;
    ushort4 v = *(const ushort4*)&y3g[(r0 + row) * 128 + col];
    float h0 = relu_np(fmaf(A3[col + 0], h2f(v.x), C3[col + 0]));
    float h1 = relu_np(fmaf(A3[col + 1], h2f(v.y), C3[col + 1]));
    float h2v = relu_np(fmaf(A3[col + 2], h2f(v.z), C3[col + 2]));
    float h3v = relu_np(fmaf(A3[col + 3], h2f(v.w), C3[col + 3]));
    uint2 pk;
    pk.x = packh2(h0, h1);
    pk.y = packh2(h2v, h3v);
    *(uint2*)&H3[row * 136 + col] = pk;
  }
#pragma unroll
  for (int i = 0; i < 2; ++i) {  // EDS fp16
    int idx = tid + i * 256;
    int row = idx >> 3, col = (idx & 7) * 4;
    float4 ev = *(const float4*)&edge[(r0 + row) * 32 + col];
    uint2 pe;
    pe.x = packh2(ev.x, ev.y);
    pe.y = packh2(ev.z, ev.w);
    *(uint2*)&EDS[row * 40 + col] = pe;
  }
  __syncthreads();

  const int l = tid & 63, w = tid >> 6;
  const int lr = l & 15, lg = l >> 4;
  f16x8 af[4];  // wave w owns row-tile w (rows w*16..w*16+15)
#pragma unroll
  for (int kb = 0; kb < 4; ++kb)
    af[kb] = *(const f16x8*)&H3[(w * 16 + lr) * 136 + kb * 32 + lg * 8];

  float mp[4][2] = {};
  for (int cg = 0; cg < 16; ++cg) {  // 64 cols per iteration
    __syncthreads();
    {
      // stage 64 W4 cols x 128 k: 1024 uint4; 4 per thread
#pragma unroll
      for (int q = 0; q < 4; ++q) {
        int idx = tid + q * 256;
        int c = idx >> 4, part = idx & 15;
        *(uint4*)&SLAB[c * 136 + part * 8] =
            *(const uint4*)&w4t[(size_t)(cg * 64 + c) * 128 + part * 8];
      }
    }
    __syncthreads();
#pragma unroll
    for (int ci = 0; ci < 4; ++ci) {
      f16x8 b[4];
#pragma unroll
      for (int kb = 0; kb < 4; ++kb)
        b[kb] = *(const f16x8*)&SLAB[(ci * 16 + lr) * 136 + kb * 32 + lg * 8];
      const int col = cg * 64 + ci * 16 + lr;
      const int d = col >> 5, hf = ci & 1;
      const float a4v = A4[col];
      f32x4 acc = {0.f, 0.f, 0.f, 0.f};
#pragma unroll
      for (int kb = 0; kb < 4; ++kb) acc = mfma16(af[kb], b[kb], acc);
#pragma unroll
      for (int r = 0; r < 4; ++r) {
        int e = w * 16 + lg * 4 + r;
        float ed = h2f(EDS[e * 40 + d]);
        mp[r][hf] = fmaf(ed * a4v, acc[r], mp[r][hf]);
      }
    }
  }

  // m0 = eds @ C4mat
  f32x4 m0[2];
  {
    f16x8 ae = *(const f16x8*)&EDS[(w * 16 + lr) * 40 + lg * 8];
#pragma unroll
    for (int ci = 0; ci < 2; ++ci) {
      f16x8 bc = *(const f16x8*)&g_c4h[(ci * 16 + lr) * 32 + lg * 8];
      f32x4 z = {0.f, 0.f, 0.f, 0.f};
      m0[ci] = mfma16(ae, bc, z);
    }
  }
  // msgs = relu(mp + m0 + bias) -> fp16 (into dead-H3 alias)
#pragma unroll
  for (int ci = 0; ci < 2; ++ci)
#pragma unroll
    for (int r = 0; r < 4; ++r) {
      int e = w * 16 + lg * 4 + r;
      int f = ci * 16 + lr;
      float v = relu_np(mp[r][ci] + m0[ci][r] + bias[f]);
      MSGu[e * 40 + f] = f2h(v);
    }
  __syncthreads();

  // GRU: gi = MSG @ Wih^T, gh = h0 @ Whh^T (ah built from global hidden)
  f16x8 am = *(const f16x8*)&MSGu[(w * 16 + lr) * 40 + lg * 8];
  f16x8 ah;
  {
    int e = w * 16 + lr;
    float4 h0a = *(const float4*)&hidden[(r0 + e) * 32 + lg * 8];
    float4 h0b = *(const float4*)&hidden[(r0 + e) * 32 + lg * 8 + 4];
    union { unsigned u[4]; f16x8 h; } uu;
    uu.u[0] = packh2(h0a.x, h0a.y);
    uu.u[1] = packh2(h0a.z, h0a.w);
    uu.u[2] = packh2(h0b.x, h0b.y);
    uu.u[3] = packh2(h0b.z, h0b.w);
    ah = uu.h;
  }
  f32x4 gi[6], gh[6];
#pragma unroll
  for (int ct = 0; ct < 6; ++ct) {
    f16x8 bi = *(const f16x8*)&wihh[(ct * 16 + lr) * 32 + lg * 8];
    f16x8 bh = *(const f16x8*)&whhh[(ct * 16 + lr) * 32 + lg * 8];
    f32x4 z = {0.f, 0.f, 0.f, 0.f};
    gi[ct] = mfma16(am, bi, z);
    gh[ct] = mfma16(ah, bh, z);
  }
#pragma unroll
  for (int r = 0; r < 4; ++r) {
    int e = w * 16 + lg * 4 + r;
#pragma unroll
    for (int hf = 0; hf < 2; ++hf) {
      int f = hf * 16 + lr;
      float xr = gi[hf][r] + bih[f];
      float xz = gi[2 + hf][r] + bih[32 + f];
      float xn = gi[4 + hf][r] + bih[64 + f];
      float hr = gh[hf][r] + bhh[f];
      float hz = gh[2 + hf][r] + bhh[32 + f];
      float hn = gh[4 + hf][r] + bhh[64 + f];
      float rg = 1.f / (1.f + __expf(-(xr + hr)));
      float zg = 1.f / (1.f + __expf(-(xz + hz)));
      float ng = tanhf(fmaf(rg, hn, xn));
      float h0v = hidden[(r0 + e) * 32 + f];
      OUTBUF[e * 32 + f] = fmaf(zg, h0v - ng, ng);
    }
  }
  __syncthreads();
#pragma unroll
  for (int i = 0; i < 2; ++i) {
    int off = tid * 4 + i * 1024;
    size_t g = r0 * 32 + off;
    float4 v = *(const float4*)&OUTBUF[off];
    *(float4*)&out[g] = v;
    *(float4*)&out[(size_t)NE * 32 + g] = v;
  }
}

extern "C" void kernel_launch(void* const* d_in, const int* in_sizes, int n_in,
                              void* d_out, int out_size, void* d_ws,
                              size_t ws_size, hipStream_t stream) {
  float* out = (float*)d_out;

  static const int EXP[21] = {
      12800000, 400000, 6400000, 6400000,
      65536, 256, 256, 65536, 256, 256, 32768, 128, 128,
      131072, 1024, 1024, 32, 3072, 3072, 96, 96};
  int bad = -1;
  if (n_in != 21) bad = 25;
  else
    for (int i = 0; i < 21; ++i)
      if (in_sizes[i] != EXP[i]) { bad = i; break; }
  if (bad < 0 && out_size != 12800000) bad = 22;
  const size_t Y1B = (size_t)NE * 256 * 2;
  if (bad < 0 && (!d_ws || ws_size < 2 * Y1B)) bad = 24;
  if (bad >= 0) {
    float code = 3.0e7f + (float)bad * 1.0e6f;
    GraphConv2_16518444221042_kernel<<<(out_size + 255) / 256, 256, 0, stream>>>(
        out, code, out_size);
    return;
  }

  const float* node   = (const float*)d_in[0];
  const int*   eidx   = (const int*)d_in[1];
  const float* edge   = (const float*)d_in[2];
  const float* hidden = (const float*)d_in[3];
  const float* W1 = (const float*)d_in[4];
  const float* g1 = (const float*)d_in[5];
  const float* b1 = (const float*)d_in[6];
  const float* W2 = (const float*)d_in[7];
  const float* g2 = (const float*)d_in[8];
  const float* b2 = (const float*)d_in[9];
  const float* W3 = (const float*)d_in[10];
  const float* g3 = (const float*)d_in[11];
  const float* b3 = (const float*)d_in[12];
  const float* W4 = (const float*)d_in[13];
  const float* g4 = (const float*)d_in[14];
  const float* b4 = (const float*)d_in[15];
  const float* bias = (const float*)d_in[16];
  const float* Wih = (const float*)d_in[17];
  const float* Whh = (const float*)d_in[18];
  const float* bih = (const float*)d_in[19];
  const float* bhh = (const float*)d_in[20];

  u16* y1 = (u16*)d_ws;
  u16* y2 = (u16*)d_ws + (size_t)NE * 256;
  u16* y3 = (u16*)d_ws;            // overwrites dead y1 after gemm3

  u16* pkA = (u16*)d_out;
  u16* w1t = pkA;
  u16* w2t = pkA + 65536;
  u16* w3t = pkA + 131072;
  u16* w4t  = y2;
  u16* wihh = y2 + 131072;
  u16* whhh = y2 + 134144;
  float* pgram = (float*)(y2 + 2097152);

  k_init<<<70, 256, 0, stream>>>(eidx);
  k_packA<<<640, 256, 0, stream>>>(W1, W2, W3, pkA);

  k_gemmP<1><<<1024, 512, 0, stream>>>(node, eidx, nullptr, w1t, y1);
  k_finalize<<<1, 256, 0, stream>>>(g1, b1, 1, 256);
  k_gemmP<2><<<1024, 512, 0, stream>>>(nullptr, nullptr, y1, w2t, y2);
  k_finalize<<<1, 256, 0, stream>>>(g2, b2, 2, 256);
  k_gemmP<3><<<1024, 512, 0, stream>>>(nullptr, nullptr, y2, w3t, y3);
  k_finalize<<<1, 256, 0, stream>>>(g3, b3, 3, 128);
  k_packB<<<537, 256, 0, stream>>>(W4, Wih, Whh, y2);  // y2 dead from here
  k_gram_m<<<GRAM_BLOCKS, 256, 0, stream>>>(y3, pgram);
  k_gramred<<<64, 256, 0, stream>>>(pgram);
  k_finalize4<<<128, 64, 0, stream>>>(W4, g4, b4);
  k_final64<<<NT64, 256, 0, stream>>>(y3, w4t, wihh, whhh, edge, hidden,
                                      bias, bih, bhh, out);
}

// Round 18
// 424.137 us; speedup vs baseline: 1.0951x; 1.0951x over previous
//
#include <hip/hip_runtime.h>
#include <hip/hip_fp16.h>

#define NE 200000
#define NT 6250
#define NT64 3125
#define GRAM_BLOCKS 512

// ---- small device-global state only --------------------------------------
__device__ float g_st[21248];
__device__ unsigned short g_c4h[1024];  // C4 transposed [f][d], fp16
__device__ int g_flag64;

#define SUM1 (&g_st[0])
#define SQ1  (&g_st[256])
#define SUM2 (&g_st[512])
#define SQ2  (&g_st[768])
#define SUM3 (&g_st[1024])
#define SQ3  (&g_st[1152])
#define GMAT (&g_st[1280])
#define CS3  (&g_st[17664])
#define A1   (&g_st[17792])
#define C1   (&g_st[18048])
#define A2   (&g_st[18304])
#define C2   (&g_st[18560])
#define A3   (&g_st[18816])
#define C3   (&g_st[18944])
#define A4   (&g_st[19072])
#define C4   (&g_st[20096])

typedef unsigned short u16;
typedef _Float16 f16x8 __attribute__((ext_vector_type(8)));
typedef float f32x4 __attribute__((ext_vector_type(4)));

__device__ __forceinline__ f32x4 mfma16(f16x8 a, f16x8 b, f32x4 c) {
  return __builtin_amdgcn_mfma_f32_16x16x32_f16(a, b, c, 0, 0, 0);
}
__device__ __forceinline__ u16 f2h(float x) {
  __half h = __float2half_rn(x);
  return *reinterpret_cast<u16*>(&h);
}
__device__ __forceinline__ float h2f(u16 s) {
  __half h = *reinterpret_cast<__half*>(&s);
  return __half2float(h);
}
__device__ __forceinline__ float relu_np(float t) { return (t < 0.f) ? 0.f : t; }
__device__ __forceinline__ unsigned packh2(float a, float b) {
  return (unsigned)f2h(a) | ((unsigned)f2h(b) << 16);
}

// bad-path fill — keeps the template's expected kernel symbol
__global__ void GraphConv2_16518444221042_kernel(float* __restrict__ out,
                                                 float v, int n) {
  int i = blockIdx.x * 256 + threadIdx.x;
  if (i < n) out[i] = v;
}

// zero stats + edge_index dtype probe (merged)
__global__ void k_init(const int* __restrict__ e) {
  int i = blockIdx.x * 256 + threadIdx.x;
  if (i < 17792) g_st[i] = 0.f;
  if (i == 0) {
    int allz = 1;
    for (int k = 1; k < 128; k += 2) allz &= (e[k] == 0);
    g_flag64 = allz;
  }
}

// ---- pack W1/W2/W3 -> fp16 k-contiguous into d_out scratch -----------------
__global__ void k_packA(const float* __restrict__ W1,
                        const float* __restrict__ W2,
                        const float* __restrict__ W3,
                        u16* __restrict__ dst) {
  int i = blockIdx.x * 256 + threadIdx.x;
  if (i >= 163840) return;
  float v;
  if (i < 65536) {
    int n = i >> 8, k = i & 255;
    v = W1[k * 256 + n];
  } else if (i < 131072) {
    int i2 = i - 65536, n = i2 >> 8, k = i2 & 255;
    v = W2[k * 256 + n];
  } else {
    int i2 = i - 131072, n = i2 >> 8, k = i2 & 255;
    v = W3[k * 128 + n];
  }
  dst[i] = f2h(v);
}

// ---- pack W4/Wih/Whh into the DEAD y2 region of d_ws (after gemm3) ---------
__global__ void k_packB(const float* __restrict__ W4,
                        const float* __restrict__ Wih,
                        const float* __restrict__ Whh,
                        u16* __restrict__ dst) {
  int i = blockIdx.x * 256 + threadIdx.x;
  if (i >= 137216) return;
  float v;
  if (i < 131072) {
    int n = i >> 7, k = i & 127;
    v = W4[(size_t)k * 1024 + n];
  } else if (i < 134144) {
    v = Wih[i - 131072];
  } else {
    v = Whh[i - 134144];
  }
  dst[i] = f2h(v);
}

__global__ void k_finalize(const float* __restrict__ g,
                           const float* __restrict__ b, int which, int C) {
  int j = threadIdx.x;
  if (j < C) {
    const float* sum = (which == 1) ? SUM1 : (which == 2) ? SUM2 : SUM3;
    const float* sq  = (which == 1) ? SQ1 : (which == 2) ? SQ2 : SQ3;
    float* aa = (which == 1) ? A1 : (which == 2) ? A2 : A3;
    float* cc = (which == 1) ? C1 : (which == 2) ? C2 : C3;
    const float invE = 1.f / (float)NE;
    float mu = sum[j] * invE;
    float var = fmaf(-mu, mu, sq[j] * invE);
    float s = rsqrtf(var + 1e-5f);
    float av = g[j] * s;
    aa[j] = av;
    cc[j] = fmaf(-av, mu, b[j]);
  }
}

__global__ __launch_bounds__(64) void k_finalize4(
    const float* __restrict__ W4, const float* __restrict__ g4,
    const float* __restrict__ b4) {
  __shared__ float wsh[128];
  const int lane = threadIdx.x;
  const float invE = 1.f / (float)NE;
  for (int j = blockIdx.x; j < 1024; j += gridDim.x) {
    float w0 = W4[lane * 1024 + j];
    float w1 = W4[(lane + 64) * 1024 + j];
    wsh[lane] = w0;
    wsh[lane + 64] = w1;
    __syncthreads();
    float s0 = 0.f, s1 = 0.f;
#pragma unroll 8
    for (int k = 0; k < 128; ++k) {
      float wk = wsh[k];
      s0 = fmaf(GMAT[lane * 128 + k], wk, s0);
      s1 = fmaf(GMAT[(lane + 64) * 128 + k], wk, s1);
    }
    float acc = w0 * s0 + w1 * s1;
    float mac = CS3[lane] * w0 + CS3[lane + 64] * w1;
#pragma unroll
    for (int off = 32; off > 0; off >>= 1) {
      acc += __shfl_down(acc, off);
      mac += __shfl_down(mac, off);
    }
    if (lane == 0) {
      float mu = mac * invE;
      float var = fmaf(-mu, mu, acc * invE);
      float s = rsqrtf(var + 1e-5f);
      float av = g4[j] * s;
      A4[j] = av;
      float cv = fmaf(-av, mu, b4[j]);
      C4[j] = cv;
      g_c4h[(j & 31) * 32 + (j >> 5)] = f2h(cv);
    }
    __syncthreads();
  }
}

// ===== persistent MFMA GEMM: register-resident weights + DOUBLE-BUFFERED ====
// H staging. Next tile's global loads issue before the barrier, landing
// under the current tile's MFMA + stores. One barrier/iteration (safe by
// buffer parity + barrier ordering).
template <int L>
__global__ __launch_bounds__(512) void k_gemmP(
    const float* __restrict__ node, const int* __restrict__ eidx,
    const u16* __restrict__ Yin, const u16* __restrict__ Wt,
    u16* __restrict__ Yout) {
  constexpr int CN = (L == 3) ? 128 : 256;
  constexpr int CTW = CN / 128;
  constexpr int LDH = 264;
  __shared__ __align__(16) u16 H[2][64 * LDH];
  __shared__ float csum_s[CN], csq_s[CN];
  const int tid = threadIdx.x;
  float* SUMo = (L == 1) ? SUM1 : (L == 2) ? SUM2 : SUM3;
  float* SQo  = (L == 1) ? SQ1 : (L == 2) ? SQ2 : SQ3;
  const float* Ain = (L == 2) ? A1 : A2;
  const float* Cin = (L == 2) ? C1 : C2;

  const int l = tid & 63, w = tid >> 6;
  const int lr = l & 15, lg = l >> 4;
  const int is64 = g_flag64;

  f16x8 bfr[CTW][8];
#pragma unroll
  for (int c = 0; c < CTW; ++c)
#pragma unroll
    for (int kb = 0; kb < 8; ++kb)
      bfr[c][kb] = *(const f16x8*)&Wt[(size_t)((w * CTW + c) * 16 + lr) * 256 +
                                      kb * 32 + lg * 8];

  if (tid < CN) { csum_s[tid] = 0.f; csq_s[tid] = 0.f; }
  float sreg[CTW] = {}, qreg[CTW] = {};

  float4 ldf[8];   // L==1 prefetch regs
  uint4 ldi[4];    // L>=2 prefetch regs

  // prologue: load first tile into regs
  {
    const int r0 = blockIdx.x * 64;
    if constexpr (L == 1) {
#pragma unroll
      for (int i = 0; i < 8; ++i) {
        int idx = tid + i * 512;
        int row = idx >> 6, col = (idx & 63) * 4;
        int sel = col >> 7, kc = col & 127;
        int j = (r0 + row) * 2 + sel;
        int v = is64 ? eidx[j * 2] : eidx[j];
        v = v < 0 ? 0 : (v > 99999 ? 99999 : v);
        ldf[i] = *(const float4*)&node[(size_t)v * 128 + kc];
      }
    } else {
#pragma unroll
      for (int i = 0; i < 4; ++i) {
        int idx = tid + i * 512;
        int row = idx >> 5, col = (idx & 31) * 8;
        ldi[i] = *(const uint4*)&Yin[(size_t)(r0 + row) * 256 + col];
      }
    }
  }

  int cur = 0;
  for (int t = blockIdx.x; t < NT64; t += gridDim.x) {
    const int r0 = t * 64;
    const int tn = t + gridDim.x;
    // convert current regs -> H[cur]
    if constexpr (L == 1) {
#pragma unroll
      for (int i = 0; i < 8; ++i) {
        int idx = tid + i * 512;
        int row = idx >> 6, col = (idx & 63) * 4;
        uint2 pk;
        pk.x = packh2(ldf[i].x, ldf[i].y);
        pk.y = packh2(ldf[i].z, ldf[i].w);
        *(uint2*)&H[cur][row * LDH + col] = pk;
      }
    } else {
#pragma unroll
      for (int i = 0; i < 4; ++i) {
        int idx = tid + i * 512;
        int row = idx >> 5, col = (idx & 31) * 8;
        const u16* sp = (const u16*)&ldi[i];
        uint4 o;
        unsigned po[4];
#pragma unroll
        for (int p = 0; p < 4; ++p) {
          float v0 = relu_np(fmaf(Ain[col + 2 * p], h2f(sp[2 * p]),
                                  Cin[col + 2 * p]));
          float v1 = relu_np(fmaf(Ain[col + 2 * p + 1], h2f(sp[2 * p + 1]),
                                  Cin[col + 2 * p + 1]));
          po[p] = packh2(v0, v1);
        }
        o.x = po[0]; o.y = po[1]; o.z = po[2]; o.w = po[3];
        *(uint4*)&H[cur][row * LDH + col] = o;
      }
    }
    // issue next tile's loads (in flight across the barrier)
    if (tn < NT64) {
      const int rn = tn * 64;
      if constexpr (L == 1) {
#pragma unroll
        for (int i = 0; i < 8; ++i) {
          int idx = tid + i * 512;
          int row = idx >> 6, col = (idx & 63) * 4;
          int sel = col >> 7, kc = col & 127;
          int j = (rn + row) * 2 + sel;
          int v = is64 ? eidx[j * 2] : eidx[j];
          v = v < 0 ? 0 : (v > 99999 ? 99999 : v);
          ldf[i] = *(const float4*)&node[(size_t)v * 128 + kc];
        }
      } else {
#pragma unroll
        for (int i = 0; i < 4; ++i) {
          int idx = tid + i * 512;
          int row = idx >> 5, col = (idx & 31) * 8;
          ldi[i] = *(const uint4*)&Yin[(size_t)(rn + row) * 256 + col];
        }
      }
    }
    __syncthreads();

    f32x4 acc[4][CTW] = {};
#pragma unroll
    for (int kb = 0; kb < 8; ++kb) {
      f16x8 a[4];
#pragma unroll
      for (int rt = 0; rt < 4; ++rt)
        a[rt] = *(const f16x8*)&H[cur][(rt * 16 + lr) * LDH + kb * 32 + lg * 8];
#pragma unroll
      for (int c = 0; c < CTW; ++c)
#pragma unroll
        for (int rt = 0; rt < 4; ++rt)
          acc[rt][c] = mfma16(a[rt], bfr[c][kb], acc[rt][c]);
    }

#pragma unroll
    for (int c = 0; c < CTW; ++c) {
      const int col = (w * CTW + c) * 16 + lr;
#pragma unroll
      for (int rt = 0; rt < 4; ++rt)
#pragma unroll
        for (int r = 0; r < 4; ++r) {
          float v = acc[rt][c][r];
          sreg[c] += v;
          qreg[c] = fmaf(v, v, qreg[c]);
          int row = rt * 16 + lg * 4 + r;
          Yout[(size_t)(r0 + row) * CN + col] = f2h(v);
        }
    }
    cur ^= 1;
  }

  __syncthreads();
#pragma unroll
  for (int c = 0; c < CTW; ++c) {
    const int col = (w * CTW + c) * 16 + lr;
    atomicAdd(&csum_s[col], sreg[c]);
    atomicAdd(&csq_s[col], qreg[c]);
  }
  __syncthreads();
  if (tid < CN) {
    atomicAdd(&SUMo[tid], csum_s[tid]);
    atomicAdd(&SQo[tid], csq_s[tid]);
  }
}

// ===== MFMA Gram: coalesced loads, shared frag pool, atomic-free ===========
__global__ __launch_bounds__(256, 2) void k_gram_m(const u16* __restrict__ y3g,
                                                   float* __restrict__ pg) {
  __shared__ u16 h3T[128 * 40];  // transposed [col][row^swz]
  __shared__ float cred[128];
  const int tid = threadIdx.x;
  const int l = tid & 63, w = tid >> 6;
  const int lr = l & 15, lg = l >> 4;
  const int c4 = (tid & 31) * 4;
  const int rb = tid >> 5;
  f32x4 acc[2][8] = {};
  float csc[4] = {0.f, 0.f, 0.f, 0.f};

  for (int t = blockIdx.x; t < NT; t += gridDim.x) {
    const size_t r0 = (size_t)t * 32;
    __syncthreads();
#pragma unroll
    for (int i = 0; i < 4; ++i) {
      int row = rb + i * 8;
      ushort4 v = *(const ushort4*)&y3g[(r0 + row) * 128 + c4];
      float h[4];
      h[0] = relu_np(fmaf(A3[c4 + 0], h2f(v.x), C3[c4 + 0]));
      h[1] = relu_np(fmaf(A3[c4 + 1], h2f(v.y), C3[c4 + 1]));
      h[2] = relu_np(fmaf(A3[c4 + 2], h2f(v.z), C3[c4 + 2]));
      h[3] = relu_np(fmaf(A3[c4 + 3], h2f(v.w), C3[c4 + 3]));
#pragma unroll
      for (int j = 0; j < 4; ++j) {
        csc[j] += h[j];
        int col = c4 + j;
        int swz = ((col >> 2) & 3) << 3;
        h3T[col * 40 + (row ^ swz)] = f2h(h[j]);
      }
    }
    __syncthreads();
    f16x8 bfr[8];
#pragma unroll
    for (int tj = 0; tj < 8; ++tj) {
      int col = tj * 16 + lr;
      int swz = ((col >> 2) & 3) << 3;
      bfr[tj] = *(const f16x8*)&h3T[col * 40 + ((lg * 8) ^ swz)];
    }
#pragma unroll
    for (int ri = 0; ri < 2; ++ri) {
      f16x8 a = bfr[w * 2 + ri];
#pragma unroll
      for (int tj = 0; tj < 8; ++tj)
        acc[ri][tj] = mfma16(a, bfr[tj], acc[ri][tj]);
    }
  }
  float* my = pg + (size_t)blockIdx.x * 16384;
#pragma unroll
  for (int ri = 0; ri < 2; ++ri)
#pragma unroll
    for (int tj = 0; tj < 8; ++tj)
#pragma unroll
      for (int r = 0; r < 4; ++r) {
        int row = (w * 2 + ri) * 16 + lg * 4 + r, col = tj * 16 + lr;
        my[row * 128 + col] = acc[ri][tj][r];
      }
  if (tid < 128) cred[tid] = 0.f;
  __syncthreads();
#pragma unroll
  for (int j = 0; j < 4; ++j) atomicAdd(&cred[c4 + j], csc[j]);
  __syncthreads();
  if (tid < 128) atomicAdd(&CS3[tid], cred[tid]);
}

__global__ void k_gramred(const float* __restrict__ pg) {
  int g = blockIdx.x * 256 + threadIdx.x;
  float s = 0.f;
  for (int p = 0; p < GRAM_BLOCKS; ++p) s += pg[(size_t)p * 16384 + g];
  GMAT[g] = s;
}

// ==== final v2 (r16-proven): 64-edge tiles, 31 KB LDS =======================
__global__ __launch_bounds__(256, 4) void k_final64(
    const u16* __restrict__ y3g, const u16* __restrict__ w4t,
    const u16* __restrict__ wihh, const u16* __restrict__ whhh,
    const float* __restrict__ edge, const float* __restrict__ hidden,
    const float* __restrict__ bias, const float* __restrict__ bih,
    const float* __restrict__ bhh, float* __restrict__ out) {
  __shared__ __align__(16) u16 H3[64 * 136];    // 17.4 KB
  __shared__ __align__(16) u16 SLAB[32 * 136];  // 8.7 KB
  __shared__ __align__(16) u16 EDS[64 * 40];    // 5.1 KB
  float* OUTBUF = (float*)H3;   // dead after af hoist
  u16* MSGu = H3 + 4096;
  const int tid = threadIdx.x;
  const size_t r0 = (size_t)blockIdx.x * 64;  // NE % 64 == 0

#pragma unroll
  for (int i = 0; i < 8; ++i) {  // H3 = relu(a3*y3+c3)
    int idx = tid + i * 256;
    int row = idx >> 5, col = (idx & 31) * 4;
    ushort4 v = *(const ushort4*)&y3g[(r0 + row) * 128 + col];
    float h0 = relu_np(fmaf(A3[col + 0], h2f(v.x), C3[col + 0]));
    float h1 = relu_np(fmaf(A3[col + 1], h2f(v.y), C3[col + 1]));
    float h2v = relu_np(fmaf(A3[col + 2], h2f(v.z), C3[col + 2]));
    float h3v = relu_np(fmaf(A3[col + 3], h2f(v.w), C3[col + 3]));
    uint2 pk;
    pk.x = packh2(h0, h1);
    pk.y = packh2(h2v, h3v);
    *(uint2*)&H3[row * 136 + col] = pk;
  }
#pragma unroll
  for (int i = 0; i < 2; ++i) {  // EDS fp16
    int idx = tid + i * 256;
    int row = idx >> 3, col = (idx & 7) * 4;
    float4 ev = *(const float4*)&edge[(r0 + row) * 32 + col];
    uint2 pe;
    pe.x = packh2(ev.x, ev.y);
    pe.y = packh2(ev.z, ev.w);
    *(uint2*)&EDS[row * 40 + col] = pe;
  }
  __syncthreads();

  const int l = tid & 63, w = tid >> 6;
  const int lr = l & 15, lg = l >> 4;
  f16x8 af[4];
#pragma unroll
  for (int kb = 0; kb < 4; ++kb)
    af[kb] = *(const f16x8*)&H3[(w * 16 + lr) * 136 + kb * 32 + lg * 8];

  float mp[4][2] = {};
  for (int cg = 0; cg < 32; ++cg) {
    __syncthreads();
    {
      int c = tid >> 3, ch = tid & 7;
#pragma unroll
      for (int q = 0; q < 2; ++q) {
        int kk = (ch + q * 8) * 8;
        *(uint4*)&SLAB[c * 136 + kk] =
            *(const uint4*)&w4t[(size_t)(cg * 32 + c) * 128 + kk];
      }
    }
    __syncthreads();
#pragma unroll
    for (int ci = 0; ci < 2; ++ci) {
      f16x8 b[4];
#pragma unroll
      for (int kb = 0; kb < 4; ++kb)
        b[kb] = *(const f16x8*)&SLAB[(ci * 16 + lr) * 136 + kb * 32 + lg * 8];
      const float a4v = A4[cg * 32 + ci * 16 + lr];
      f32x4 acc = {0.f, 0.f, 0.f, 0.f};
#pragma unroll
      for (int kb = 0; kb < 4; ++kb) acc = mfma16(af[kb], b[kb], acc);
#pragma unroll
      for (int r = 0; r < 4; ++r) {
        int e = w * 16 + lg * 4 + r;
        float ed = h2f(EDS[e * 40 + cg]);
        mp[r][ci] = fmaf(ed * a4v, acc[r], mp[r][ci]);
      }
    }
  }

  f32x4 m0[2];
  {
    f16x8 ae = *(const f16x8*)&EDS[(w * 16 + lr) * 40 + lg * 8];
#pragma unroll
    for (int ci = 0; ci < 2; ++ci) {
      f16x8 bc = *(const f16x8*)&g_c4h[(ci * 16 + lr) * 32 + lg * 8];
      f32x4 z = {0.f, 0.f, 0.f, 0.f};
      m0[ci] = mfma16(ae, bc, z);
    }
  }
#pragma unroll
  for (int ci = 0; ci < 2; ++ci)
#pragma unroll
    for (int r = 0; r < 4; ++r) {
      int e = w * 16 + lg * 4 + r;
      int f = ci * 16 + lr;
      float v = relu_np(mp[r][ci] + m0[ci][r] + bias[f]);
      MSGu[e * 40 + f] = f2h(v);
    }
  __syncthreads();

  f16x8 am = *(const f16x8*)&MSGu[(w * 16 + lr) * 40 + lg * 8];
  f16x8 ah;
  {
    int e = w * 16 + lr;
    float4 h0a = *(const float4*)&hidden[(r0 + e) * 32 + lg * 8];
    float4 h0b = *(const float4*)&hidden[(r0 + e) * 32 + lg * 8 + 4];
    union { unsigned u[4]; f16x8 h; } uu;
    uu.u[0] = packh2(h0a.x, h0a.y);
    uu.u[1] = packh2(h0a.z, h0a.w);
    uu.u[2] = packh2(h0b.x, h0b.y);
    uu.u[3] = packh2(h0b.z, h0b.w);
    ah = uu.h;
  }
  f32x4 gi[6], gh[6];
#pragma unroll
  for (int ct = 0; ct < 6; ++ct) {
    f16x8 bi = *(const f16x8*)&wihh[(ct * 16 + lr) * 32 + lg * 8];
    f16x8 bh = *(const f16x8*)&whhh[(ct * 16 + lr) * 32 + lg * 8];
    f32x4 z = {0.f, 0.f, 0.f, 0.f};
    gi[ct] = mfma16(am, bi, z);
    gh[ct] = mfma16(ah, bh, z);
  }
#pragma unroll
  for (int r = 0; r < 4; ++r) {
    int e = w * 16 + lg * 4 + r;
#pragma unroll
    for (int hf = 0; hf < 2; ++hf) {
      int f = hf * 16 + lr;
      float xr = gi[hf][r] + bih[f];
      float xz = gi[2 + hf][r] + bih[32 + f];
      float xn = gi[4 + hf][r] + bih[64 + f];
      float hr = gh[hf][r] + bhh[f];
      float hz = gh[2 + hf][r] + bhh[32 + f];
      float hn = gh[4 + hf][r] + bhh[64 + f];
      float rg = 1.f / (1.f + __expf(-(xr + hr)));
      float zg = 1.f / (1.f + __expf(-(xz + hz)));
      float ng = tanhf(fmaf(rg, hn, xn));
      float h0v = hidden[(r0 + e) * 32 + f];
      OUTBUF[e * 32 + f] = fmaf(zg, h0v - ng, ng);
    }
  }
  __syncthreads();
#pragma unroll
  for (int i = 0; i < 2; ++i) {
    int off = tid * 4 + i * 1024;
    size_t g = r0 * 32 + off;
    float4 v = *(const float4*)&OUTBUF[off];
    *(float4*)&out[g] = v;
    *(float4*)&out[(size_t)NE * 32 + g] = v;
  }
}

extern "C" void kernel_launch(void* const* d_in, const int* in_sizes, int n_in,
                              void* d_out, int out_size, void* d_ws,
                              size_t ws_size, hipStream_t stream) {
  float* out = (float*)d_out;

  static const int EXP[21] = {
      12800000, 400000, 6400000, 6400000,
      65536, 256, 256, 65536, 256, 256, 32768, 128, 128,
      131072, 1024, 1024, 32, 3072, 3072, 96, 96};
  int bad = -1;
  if (n_in != 21) bad = 25;
  else
    for (int i = 0; i < 21; ++i)
      if (in_sizes[i] != EXP[i]) { bad = i; break; }
  if (bad < 0 && out_size != 12800000) bad = 22;
  const size_t Y1B = (size_t)NE * 256 * 2;
  if (bad < 0 && (!d_ws || ws_size < 2 * Y1B)) bad = 24;
  if (bad >= 0) {
    float code = 3.0e7f + (float)bad * 1.0e6f;
    GraphConv2_16518444221042_kernel<<<(out_size + 255) / 256, 256, 0, stream>>>(
        out, code, out_size);
    return;
  }

  const float* node   = (const float*)d_in[0];
  const int*   eidx   = (const int*)d_in[1];
  const float* edge   = (const float*)d_in[2];
  const float* hidden = (const float*)d_in[3];
  const float* W1 = (const float*)d_in[4];
  const float* g1 = (const float*)d_in[5];
  const float* b1 = (const float*)d_in[6];
  const float* W2 = (const float*)d_in[7];
  const float* g2 = (const float*)d_in[8];
  const float* b2 = (const float*)d_in[9];
  const float* W3 = (const float*)d_in[10];
  const float* g3 = (const float*)d_in[11];
  const float* b3 = (const float*)d_in[12];
  const float* W4 = (const float*)d_in[13];
  const float* g4 = (const float*)d_in[14];
  const float* b4 = (const float*)d_in[15];
  const float* bias = (const float*)d_in[16];
  const float* Wih = (const float*)d_in[17];
  const float* Whh = (const float*)d_in[18];
  const float* bih = (const float*)d_in[19];
  const float* bhh = (const float*)d_in[20];

  u16* y1 = (u16*)d_ws;
  u16* y2 = (u16*)d_ws + (size_t)NE * 256;
  u16* y3 = (u16*)d_ws;            // overwrites dead y1 after gemm3

  u16* pkA = (u16*)d_out;
  u16* w1t = pkA;
  u16* w2t = pkA + 65536;
  u16* w3t = pkA + 131072;
  u16* w4t  = y2;
  u16* wihh = y2 + 131072;
  u16* whhh = y2 + 134144;
  float* pgram = (float*)(y2 + 2097152);

  k_init<<<70, 256, 0, stream>>>(eidx);
  k_packA<<<640, 256, 0, stream>>>(W1, W2, W3, pkA);

  k_gemmP<1><<<512, 512, 0, stream>>>(node, eidx, nullptr, w1t, y1);
  k_finalize<<<1, 256, 0, stream>>>(g1, b1, 1, 256);
  k_gemmP<2><<<512, 512, 0, stream>>>(nullptr, nullptr, y1, w2t, y2);
  k_finalize<<<1, 256, 0, stream>>>(g2, b2, 2, 256);
  k_gemmP<3><<<512, 512, 0, stream>>>(nullptr, nullptr, y2, w3t, y3);
  k_finalize<<<1, 256, 0, stream>>>(g3, b3, 3, 128);
  k_packB<<<537, 256, 0, stream>>>(W4, Wih, Whh, y2);  // y2 dead from here
  k_gram_m<<<GRAM_BLOCKS, 256, 0, stream>>>(y3, pgram);
  k_gramred<<<64, 256, 0, stream>>>(pgram);
  k_finalize4<<<128, 64, 0, stream>>>(W4, g4, b4);
  k_final64<<<NT64, 256, 0, stream>>>(y3, w4t, wihh, whhh, edge, hidden,
                                      bias, bih, bhh, out);
}

// Round 19
// 417.890 us; speedup vs baseline: 1.1114x; 1.0149x over previous
//
#include <hip/hip_runtime.h>
#include <hip/hip_fp16.h>

#define NE 200000
#define NT 6250
#define NT64 3125
#define GRAM_BLOCKS 512

// ---- small device-global state only --------------------------------------
__device__ float g_st[21248];
__device__ unsigned short g_c4h[1024];  // C4 transposed [f][d], fp16
__device__ int g_flag64;

#define SUM1 (&g_st[0])
#define SQ1  (&g_st[256])
#define SUM2 (&g_st[512])
#define SQ2  (&g_st[768])
#define SUM3 (&g_st[1024])
#define SQ3  (&g_st[1152])
#define GMAT (&g_st[1280])
#define CS3  (&g_st[17664])
#define A1   (&g_st[17792])
#define C1   (&g_st[18048])
#define A2   (&g_st[18304])
#define C2   (&g_st[18560])
#define A3   (&g_st[18816])
#define C3   (&g_st[18944])
#define A4   (&g_st[19072])
#define C4   (&g_st[20096])

typedef unsigned short u16;
typedef _Float16 f16x8 __attribute__((ext_vector_type(8)));
typedef float f32x4 __attribute__((ext_vector_type(4)));

__device__ __forceinline__ f32x4 mfma16(f16x8 a, f16x8 b, f32x4 c) {
  return __builtin_amdgcn_mfma_f32_16x16x32_f16(a, b, c, 0, 0, 0);
}
__device__ __forceinline__ u16 f2h(float x) {
  __half h = __float2half_rn(x);
  return *reinterpret_cast<u16*>(&h);
}
__device__ __forceinline__ float h2f(u16 s) {
  __half h = *reinterpret_cast<__half*>(&s);
  return __half2float(h);
}
__device__ __forceinline__ float relu_np(float t) { return (t < 0.f) ? 0.f : t; }
__device__ __forceinline__ unsigned packh2(float a, float b) {
  return (unsigned)f2h(a) | ((unsigned)f2h(b) << 16);
}

// bad-path fill — keeps the template's expected kernel symbol
__global__ void GraphConv2_16518444221042_kernel(float* __restrict__ out,
                                                 float v, int n) {
  int i = blockIdx.x * 256 + threadIdx.x;
  if (i < n) out[i] = v;
}

// zero stats + edge_index dtype probe (merged)
__global__ void k_init(const int* __restrict__ e) {
  int i = blockIdx.x * 256 + threadIdx.x;
  if (i < 17792) g_st[i] = 0.f;
  if (i == 0) {
    int allz = 1;
    for (int k = 1; k < 128; k += 2) allz &= (e[k] == 0);
    g_flag64 = allz;
  }
}

// ---- pack W1/W2/W3 -> fp16 k-contiguous into d_out scratch -----------------
__global__ void k_packA(const float* __restrict__ W1,
                        const float* __restrict__ W2,
                        const float* __restrict__ W3,
                        u16* __restrict__ dst) {
  int i = blockIdx.x * 256 + threadIdx.x;
  if (i >= 163840) return;
  float v;
  if (i < 65536) {
    int n = i >> 8, k = i & 255;
    v = W1[k * 256 + n];
  } else if (i < 131072) {
    int i2 = i - 65536, n = i2 >> 8, k = i2 & 255;
    v = W2[k * 256 + n];
  } else {
    int i2 = i - 131072, n = i2 >> 8, k = i2 & 255;
    v = W3[k * 128 + n];
  }
  dst[i] = f2h(v);
}

// ---- pack W4*A4 / Wih / Whh into DEAD y2 (runs AFTER finalize4) ------------
__global__ void k_packB(const float* __restrict__ W4,
                        const float* __restrict__ Wih,
                        const float* __restrict__ Whh,
                        u16* __restrict__ dst) {
  int i = blockIdx.x * 256 + threadIdx.x;
  if (i >= 137216) return;
  float v;
  if (i < 131072) {
    int n = i >> 7, k = i & 127;
    v = W4[(size_t)k * 1024 + n] * A4[n];  // A4 folded in (finalize4 done)
  } else if (i < 134144) {
    v = Wih[i - 131072];
  } else {
    v = Whh[i - 134144];
  }
  dst[i] = f2h(v);
}

__global__ void k_finalize(const float* __restrict__ g,
                           const float* __restrict__ b, int which, int C) {
  int j = threadIdx.x;
  if (j < C) {
    const float* sum = (which == 1) ? SUM1 : (which == 2) ? SUM2 : SUM3;
    const float* sq  = (which == 1) ? SQ1 : (which == 2) ? SQ2 : SQ3;
    float* aa = (which == 1) ? A1 : (which == 2) ? A2 : A3;
    float* cc = (which == 1) ? C1 : (which == 2) ? C2 : C3;
    const float invE = 1.f / (float)NE;
    float mu = sum[j] * invE;
    float var = fmaf(-mu, mu, sq[j] * invE);
    float s = rsqrtf(var + 1e-5f);
    float av = g[j] * s;
    aa[j] = av;
    cc[j] = fmaf(-av, mu, b[j]);
  }
}

__global__ __launch_bounds__(64) void k_finalize4(
    const float* __restrict__ W4, const float* __restrict__ g4,
    const float* __restrict__ b4) {
  __shared__ float wsh[128];
  const int lane = threadIdx.x;
  const float invE = 1.f / (float)NE;
  for (int j = blockIdx.x; j < 1024; j += gridDim.x) {
    float w0 = W4[lane * 1024 + j];
    float w1 = W4[(lane + 64) * 1024 + j];
    wsh[lane] = w0;
    wsh[lane + 64] = w1;
    __syncthreads();
    float s0 = 0.f, s1 = 0.f;
#pragma unroll 8
    for (int k = 0; k < 128; ++k) {
      float wk = wsh[k];
      s0 = fmaf(GMAT[lane * 128 + k], wk, s0);
      s1 = fmaf(GMAT[(lane + 64) * 128 + k], wk, s1);
    }
    float acc = w0 * s0 + w1 * s1;
    float mac = CS3[lane] * w0 + CS3[lane + 64] * w1;
#pragma unroll
    for (int off = 32; off > 0; off >>= 1) {
      acc += __shfl_down(acc, off);
      mac += __shfl_down(mac, off);
    }
    if (lane == 0) {
      float mu = mac * invE;
      float var = fmaf(-mu, mu, acc * invE);
      float s = rsqrtf(var + 1e-5f);
      float av = g4[j] * s;
      A4[j] = av;
      float cv = fmaf(-av, mu, b4[j]);
      C4[j] = cv;
      g_c4h[(j & 31) * 32 + (j >> 5)] = f2h(cv);
    }
    __syncthreads();
  }
}

// ===== persistent MFMA GEMM: register-resident weights + DOUBLE-BUFFERED ====
template <int L>
__global__ __launch_bounds__(512) void k_gemmP(
    const float* __restrict__ node, const int* __restrict__ eidx,
    const u16* __restrict__ Yin, const u16* __restrict__ Wt,
    u16* __restrict__ Yout) {
  constexpr int CN = (L == 3) ? 128 : 256;
  constexpr int CTW = CN / 128;
  constexpr int LDH = 264;
  __shared__ __align__(16) u16 H[2][64 * LDH];
  __shared__ float csum_s[CN], csq_s[CN];
  const int tid = threadIdx.x;
  float* SUMo = (L == 1) ? SUM1 : (L == 2) ? SUM2 : SUM3;
  float* SQo  = (L == 1) ? SQ1 : (L == 2) ? SQ2 : SQ3;
  const float* Ain = (L == 2) ? A1 : A2;
  const float* Cin = (L == 2) ? C1 : C2;

  const int l = tid & 63, w = tid >> 6;
  const int lr = l & 15, lg = l >> 4;
  const int is64 = g_flag64;

  f16x8 bfr[CTW][8];
#pragma unroll
  for (int c = 0; c < CTW; ++c)
#pragma unroll
    for (int kb = 0; kb < 8; ++kb)
      bfr[c][kb] = *(const f16x8*)&Wt[(size_t)((w * CTW + c) * 16 + lr) * 256 +
                                      kb * 32 + lg * 8];

  if (tid < CN) { csum_s[tid] = 0.f; csq_s[tid] = 0.f; }
  float sreg[CTW] = {}, qreg[CTW] = {};

  float4 ldf[8];
  uint4 ldi[4];

  {
    const int r0 = blockIdx.x * 64;
    if constexpr (L == 1) {
#pragma unroll
      for (int i = 0; i < 8; ++i) {
        int idx = tid + i * 512;
        int row = idx >> 6, col = (idx & 63) * 4;
        int sel = col >> 7, kc = col & 127;
        int j = (r0 + row) * 2 + sel;
        int v = is64 ? eidx[j * 2] : eidx[j];
        v = v < 0 ? 0 : (v > 99999 ? 99999 : v);
        ldf[i] = *(const float4*)&node[(size_t)v * 128 + kc];
      }
    } else {
#pragma unroll
      for (int i = 0; i < 4; ++i) {
        int idx = tid + i * 512;
        int row = idx >> 5, col = (idx & 31) * 8;
        ldi[i] = *(const uint4*)&Yin[(size_t)(r0 + row) * 256 + col];
      }
    }
  }

  int cur = 0;
  for (int t = blockIdx.x; t < NT64; t += gridDim.x) {
    const int r0 = t * 64;
    const int tn = t + gridDim.x;
    if constexpr (L == 1) {
#pragma unroll
      for (int i = 0; i < 8; ++i) {
        int idx = tid + i * 512;
        int row = idx >> 6, col = (idx & 63) * 4;
        uint2 pk;
        pk.x = packh2(ldf[i].x, ldf[i].y);
        pk.y = packh2(ldf[i].z, ldf[i].w);
        *(uint2*)&H[cur][row * LDH + col] = pk;
      }
    } else {
#pragma unroll
      for (int i = 0; i < 4; ++i) {
        int idx = tid + i * 512;
        int row = idx >> 5, col = (idx & 31) * 8;
        const u16* sp = (const u16*)&ldi[i];
        uint4 o;
        unsigned po[4];
#pragma unroll
        for (int p = 0; p < 4; ++p) {
          float v0 = relu_np(fmaf(Ain[col + 2 * p], h2f(sp[2 * p]),
                                  Cin[col + 2 * p]));
          float v1 = relu_np(fmaf(Ain[col + 2 * p + 1], h2f(sp[2 * p + 1]),
                                  Cin[col + 2 * p + 1]));
          po[p] = packh2(v0, v1);
        }
        o.x = po[0]; o.y = po[1]; o.z = po[2]; o.w = po[3];
        *(uint4*)&H[cur][row * LDH + col] = o;
      }
    }
    if (tn < NT64) {
      const int rn = tn * 64;
      if constexpr (L == 1) {
#pragma unroll
        for (int i = 0; i < 8; ++i) {
          int idx = tid + i * 512;
          int row = idx >> 6, col = (idx & 63) * 4;
          int sel = col >> 7, kc = col & 127;
          int j = (rn + row) * 2 + sel;
          int v = is64 ? eidx[j * 2] : eidx[j];
          v = v < 0 ? 0 : (v > 99999 ? 99999 : v);
          ldf[i] = *(const float4*)&node[(size_t)v * 128 + kc];
        }
      } else {
#pragma unroll
        for (int i = 0; i < 4; ++i) {
          int idx = tid + i * 512;
          int row = idx >> 5, col = (idx & 31) * 8;
          ldi[i] = *(const uint4*)&Yin[(size_t)(rn + row) * 256 + col];
        }
      }
    }
    __syncthreads();

    f32x4 acc[4][CTW] = {};
#pragma unroll
    for (int kb = 0; kb < 8; ++kb) {
      f16x8 a[4];
#pragma unroll
      for (int rt = 0; rt < 4; ++rt)
        a[rt] = *(const f16x8*)&H[cur][(rt * 16 + lr) * LDH + kb * 32 + lg * 8];
#pragma unroll
      for (int c = 0; c < CTW; ++c)
#pragma unroll
        for (int rt = 0; rt < 4; ++rt)
          acc[rt][c] = mfma16(a[rt], bfr[c][kb], acc[rt][c]);
    }

#pragma unroll
    for (int c = 0; c < CTW; ++c) {
      const int col = (w * CTW + c) * 16 + lr;
#pragma unroll
      for (int rt = 0; rt < 4; ++rt)
#pragma unroll
        for (int r = 0; r < 4; ++r) {
          float v = acc[rt][c][r];
          sreg[c] += v;
          qreg[c] = fmaf(v, v, qreg[c]);
          int row = rt * 16 + lg * 4 + r;
          Yout[(size_t)(r0 + row) * CN + col] = f2h(v);
        }
    }
    cur ^= 1;
  }

  __syncthreads();
#pragma unroll
  for (int c = 0; c < CTW; ++c) {
    const int col = (w * CTW + c) * 16 + lr;
    atomicAdd(&csum_s[col], sreg[c]);
    atomicAdd(&csq_s[col], qreg[c]);
  }
  __syncthreads();
  if (tid < CN) {
    atomicAdd(&SUMo[tid], csum_s[tid]);
    atomicAdd(&SQo[tid], csq_s[tid]);
  }
}

// ===== MFMA Gram: coalesced loads, shared frag pool, atomic-free ===========
__global__ __launch_bounds__(256, 2) void k_gram_m(const u16* __restrict__ y3g,
                                                   float* __restrict__ pg) {
  __shared__ u16 h3T[128 * 40];
  __shared__ float cred[128];
  const int tid = threadIdx.x;
  const int l = tid & 63, w = tid >> 6;
  const int lr = l & 15, lg = l >> 4;
  const int c4 = (tid & 31) * 4;
  const int rb = tid >> 5;
  f32x4 acc[2][8] = {};
  float csc[4] = {0.f, 0.f, 0.f, 0.f};

  for (int t = blockIdx.x; t < NT; t += gridDim.x) {
    const size_t r0 = (size_t)t * 32;
    __syncthreads();
#pragma unroll
    for (int i = 0; i < 4; ++i) {
      int row = rb + i * 8;
      ushort4 v = *(const ushort4*)&y3g[(r0 + row) * 128 + c4];
      float h[4];
      h[0] = relu_np(fmaf(A3[c4 + 0], h2f(v.x), C3[c4 + 0]));
      h[1] = relu_np(fmaf(A3[c4 + 1], h2f(v.y), C3[c4 + 1]));
      h[2] = relu_np(fmaf(A3[c4 + 2], h2f(v.z), C3[c4 + 2]));
      h[3] = relu_np(fmaf(A3[c4 + 3], h2f(v.w), C3[c4 + 3]));
#pragma unroll
      for (int j = 0; j < 4; ++j) {
        csc[j] += h[j];
        int col = c4 + j;
        int swz = ((col >> 2) & 3) << 3;
        h3T[col * 40 + (row ^ swz)] = f2h(h[j]);
      }
    }
    __syncthreads();
    f16x8 bfr[8];
#pragma unroll
    for (int tj = 0; tj < 8; ++tj) {
      int col = tj * 16 + lr;
      int swz = ((col >> 2) & 3) << 3;
      bfr[tj] = *(const f16x8*)&h3T[col * 40 + ((lg * 8) ^ swz)];
    }
#pragma unroll
    for (int ri = 0; ri < 2; ++ri) {
      f16x8 a = bfr[w * 2 + ri];
#pragma unroll
      for (int tj = 0; tj < 8; ++tj)
        acc[ri][tj] = mfma16(a, bfr[tj], acc[ri][tj]);
    }
  }
  float* my = pg + (size_t)blockIdx.x * 16384;
#pragma unroll
  for (int ri = 0; ri < 2; ++ri)
#pragma unroll
    for (int tj = 0; tj < 8; ++tj)
#pragma unroll
      for (int r = 0; r < 4; ++r) {
        int row = (w * 2 + ri) * 16 + lg * 4 + r, col = tj * 16 + lr;
        my[row * 128 + col] = acc[ri][tj][r];
      }
  if (tid < 128) cred[tid] = 0.f;
  __syncthreads();
#pragma unroll
  for (int j = 0; j < 4; ++j) atomicAdd(&cred[c4 + j], csc[j]);
  __syncthreads();
  if (tid < 128) atomicAdd(&CS3[tid], cred[tid]);
}

__global__ void k_gramred(const float* __restrict__ pg) {
  int g = blockIdx.x * 256 + threadIdx.x;
  float s = 0.f;
  for (int p = 0; p < GRAM_BLOCKS; ++p) s += pg[(size_t)p * 16384 + g];
  GMAT[g] = s;
}

// ==== final v4: 64-edge tiles, SLAB double-buffered, A4 pre-folded ==========
__global__ __launch_bounds__(256, 4) void k_final64(
    const u16* __restrict__ y3g, const u16* __restrict__ w4t,
    const u16* __restrict__ wihh, const u16* __restrict__ whhh,
    const float* __restrict__ edge, const float* __restrict__ hidden,
    const float* __restrict__ bias, const float* __restrict__ bih,
    const float* __restrict__ bhh, float* __restrict__ out) {
  __shared__ __align__(16) u16 H3[64 * 136];       // 17.4 KB
  __shared__ __align__(16) u16 SLAB[2][32 * 136];  // 17.4 KB (dbuf)
  __shared__ __align__(16) u16 EDS[64 * 40];       // 5.1 KB
  float* OUTBUF = (float*)H3;   // dead after af hoist
  u16* MSGu = H3 + 4096;
  const int tid = threadIdx.x;
  const size_t r0 = (size_t)blockIdx.x * 64;  // NE % 64 == 0

#pragma unroll
  for (int i = 0; i < 8; ++i) {  // H3 = relu(a3*y3+c3)
    int idx = tid + i * 256;
    int row = idx >> 5, col = (idx & 31) * 4;
    ushort4 v = *(const ushort4*)&y3g[(r0 + row) * 128 + col];
    float h0 = relu_np(fmaf(A3[col + 0], h2f(v.x), C3[col + 0]));
    float h1 = relu_np(fmaf(A3[col + 1], h2f(v.y), C3[col + 1]));
    float h2v = relu_np(fmaf(A3[col + 2], h2f(v.z), C3[col + 2]));
    float h3v = relu_np(fmaf(A3[col + 3], h2f(v.w), C3[col + 3]));
    uint2 pk;
    pk.x = packh2(h0, h1);
    pk.y = packh2(h2v, h3v);
    *(uint2*)&H3[row * 136 + col] = pk;
  }
#pragma unroll
  for (int i = 0; i < 2; ++i) {  // EDS fp16
    int idx = tid + i * 256;
    int row = idx >> 3, col = (idx & 7) * 4;
    float4 ev = *(const float4*)&edge[(r0 + row) * 32 + col];
    uint2 pe;
    pe.x = packh2(ev.x, ev.y);
    pe.y = packh2(ev.z, ev.w);
    *(uint2*)&EDS[row * 40 + col] = pe;
  }
  __syncthreads();

  const int l = tid & 63, w = tid >> 6;
  const int lr = l & 15, lg = l >> 4;
  f16x8 af[4];
#pragma unroll
  for (int kb = 0; kb < 4; ++kb)
    af[kb] = *(const f16x8*)&H3[(w * 16 + lr) * 136 + kb * 32 + lg * 8];

  // SLAB double-buffer: prefetch cg+1 into regs before each barrier
  const int sc = tid >> 3, sch = tid & 7;
  uint4 pre0 = *(const uint4*)&w4t[(size_t)sc * 128 + sch * 8];
  uint4 pre1 = *(const uint4*)&w4t[(size_t)sc * 128 + (sch + 8) * 8];

  float mp[4][2] = {};
  int cur = 0;
  for (int cg = 0; cg < 32; ++cg) {
    *(uint4*)&SLAB[cur][sc * 136 + sch * 8] = pre0;
    *(uint4*)&SLAB[cur][sc * 136 + (sch + 8) * 8] = pre1;
    if (cg + 1 < 32) {
      pre0 = *(const uint4*)&w4t[(size_t)((cg + 1) * 32 + sc) * 128 + sch * 8];
      pre1 =
          *(const uint4*)&w4t[(size_t)((cg + 1) * 32 + sc) * 128 + (sch + 8) * 8];
    }
    __syncthreads();
    float edv[4];
#pragma unroll
    for (int r = 0; r < 4; ++r)
      edv[r] = h2f(EDS[(w * 16 + lg * 4 + r) * 40 + cg]);
#pragma unroll
    for (int ci = 0; ci < 2; ++ci) {
      f16x8 b[4];
#pragma unroll
      for (int kb = 0; kb < 4; ++kb)
        b[kb] =
            *(const f16x8*)&SLAB[cur][(ci * 16 + lr) * 136 + kb * 32 + lg * 8];
      f32x4 acc = {0.f, 0.f, 0.f, 0.f};
#pragma unroll
      for (int kb = 0; kb < 4; ++kb) acc = mfma16(af[kb], b[kb], acc);
#pragma unroll
      for (int r = 0; r < 4; ++r)
        mp[r][ci] = fmaf(edv[r], acc[r], mp[r][ci]);
    }
    cur ^= 1;
  }

  f32x4 m0[2];
  {
    f16x8 ae = *(const f16x8*)&EDS[(w * 16 + lr) * 40 + lg * 8];
#pragma unroll
    for (int ci = 0; ci < 2; ++ci) {
      f16x8 bc = *(const f16x8*)&g_c4h[(ci * 16 + lr) * 32 + lg * 8];
      f32x4 z = {0.f, 0.f, 0.f, 0.f};
      m0[ci] = mfma16(ae, bc, z);
    }
  }
#pragma unroll
  for (int ci = 0; ci < 2; ++ci)
#pragma unroll
    for (int r = 0; r < 4; ++r) {
      int e = w * 16 + lg * 4 + r;
      int f = ci * 16 + lr;
      float v = relu_np(mp[r][ci] + m0[ci][r] + bias[f]);
      MSGu[e * 40 + f] = f2h(v);
    }
  __syncthreads();

  f16x8 am = *(const f16x8*)&MSGu[(w * 16 + lr) * 40 + lg * 8];
  f16x8 ah;
  {
    int e = w * 16 + lr;
    float4 h0a = *(const float4*)&hidden[(r0 + e) * 32 + lg * 8];
    float4 h0b = *(const float4*)&hidden[(r0 + e) * 32 + lg * 8 + 4];
    union { unsigned u[4]; f16x8 h; } uu;
    uu.u[0] = packh2(h0a.x, h0a.y);
    uu.u[1] = packh2(h0a.z, h0a.w);
    uu.u[2] = packh2(h0b.x, h0b.y);
    uu.u[3] = packh2(h0b.z, h0b.w);
    ah = uu.h;
  }
  f32x4 gi[6], gh[6];
#pragma unroll
  for (int ct = 0; ct < 6; ++ct) {
    f16x8 bi = *(const f16x8*)&wihh[(ct * 16 + lr) * 32 + lg * 8];
    f16x8 bh = *(const f16x8*)&whhh[(ct * 16 + lr) * 32 + lg * 8];
    f32x4 z = {0.f, 0.f, 0.f, 0.f};
    gi[ct] = mfma16(am, bi, z);
    gh[ct] = mfma16(ah, bh, z);
  }
#pragma unroll
  for (int r = 0; r < 4; ++r) {
    int e = w * 16 + lg * 4 + r;
#pragma unroll
    for (int hf = 0; hf < 2; ++hf) {
      int f = hf * 16 + lr;
      float xr = gi[hf][r] + bih[f];
      float xz = gi[2 + hf][r] + bih[32 + f];
      float xn = gi[4 + hf][r] + bih[64 + f];
      float hr = gh[hf][r] + bhh[f];
      float hz = gh[2 + hf][r] + bhh[32 + f];
      float hn = gh[4 + hf][r] + bhh[64 + f];
      float rg = 1.f / (1.f + __expf(-(xr + hr)));
      float zg = 1.f / (1.f + __expf(-(xz + hz)));
      float ng = tanhf(fmaf(rg, hn, xn));
      float h0v = hidden[(r0 + e) * 32 + f];
      OUTBUF[e * 32 + f] = fmaf(zg, h0v - ng, ng);
    }
  }
  __syncthreads();
#pragma unroll
  for (int i = 0; i < 2; ++i) {
    int off = tid * 4 + i * 1024;
    size_t g = r0 * 32 + off;
    float4 v = *(const float4*)&OUTBUF[off];
    *(float4*)&out[g] = v;
    *(float4*)&out[(size_t)NE * 32 + g] = v;
  }
}

extern "C" void kernel_launch(void* const* d_in, const int* in_sizes, int n_in,
                              void* d_out, int out_size, void* d_ws,
                              size_t ws_size, hipStream_t stream) {
  float* out = (float*)d_out;

  static const int EXP[21] = {
      12800000, 400000, 6400000, 6400000,
      65536, 256, 256, 65536, 256, 256, 32768, 128, 128,
      131072, 1024, 1024, 32, 3072, 3072, 96, 96};
  int bad = -1;
  if (n_in != 21) bad = 25;
  else
    for (int i = 0; i < 21; ++i)
      if (in_sizes[i] != EXP[i]) { bad = i; break; }
  if (bad < 0 && out_size != 12800000) bad = 22;
  const size_t Y1B = (size_t)NE * 256 * 2;
  if (bad < 0 && (!d_ws || ws_size < 2 * Y1B)) bad = 24;
  if (bad >= 0) {
    float code = 3.0e7f + (float)bad * 1.0e6f;
    GraphConv2_16518444221042_kernel<<<(out_size + 255) / 256, 256, 0, stream>>>(
        out, code, out_size);
    return;
  }

  const float* node   = (const float*)d_in[0];
  const int*   eidx   = (const int*)d_in[1];
  const float* edge   = (const float*)d_in[2];
  const float* hidden = (const float*)d_in[3];
  const float* W1 = (const float*)d_in[4];
  const float* g1 = (const float*)d_in[5];
  const float* b1 = (const float*)d_in[6];
  const float* W2 = (const float*)d_in[7];
  const float* g2 = (const float*)d_in[8];
  const float* b2 = (const float*)d_in[9];
  const float* W3 = (const float*)d_in[10];
  const float* g3 = (const float*)d_in[11];
  const float* b3 = (const float*)d_in[12];
  const float* W4 = (const float*)d_in[13];
  const float* g4 = (const float*)d_in[14];
  const float* b4 = (const float*)d_in[15];
  const float* bias = (const float*)d_in[16];
  const float* Wih = (const float*)d_in[17];
  const float* Whh = (const float*)d_in[18];
  const float* bih = (const float*)d_in[19];
  const float* bhh = (const float*)d_in[20];

  u16* y1 = (u16*)d_ws;
  u16* y2 = (u16*)d_ws + (size_t)NE * 256;
  u16* y3 = (u16*)d_ws;            // overwrites dead y1 after gemm3

  u16* pkA = (u16*)d_out;
  u16* w1t = pkA;
  u16* w2t = pkA + 65536;
  u16* w3t = pkA + 131072;
  u16* w4t  = y2;
  u16* wihh = y2 + 131072;
  u16* whhh = y2 + 134144;
  float* pgram = (float*)(y2 + 2097152);

  k_init<<<70, 256, 0, stream>>>(eidx);
  k_packA<<<640, 256, 0, stream>>>(W1, W2, W3, pkA);

  k_gemmP<1><<<512, 512, 0, stream>>>(node, eidx, nullptr, w1t, y1);
  k_finalize<<<1, 256, 0, stream>>>(g1, b1, 1, 256);
  k_gemmP<2><<<512, 512, 0, stream>>>(nullptr, nullptr, y1, w2t, y2);
  k_finalize<<<1, 256, 0, stream>>>(g2, b2, 2, 256);
  k_gemmP<3><<<512, 512, 0, stream>>>(nullptr, nullptr, y2, w3t, y3);
  k_finalize<<<1, 256, 0, stream>>>(g3, b3, 3, 128);
  k_gram_m<<<GRAM_BLOCKS, 256, 0, stream>>>(y3, pgram);
  k_gramred<<<64, 256, 0, stream>>>(pgram);
  k_finalize4<<<128, 64, 0, stream>>>(W4, g4, b4);
  k_packB<<<537, 256, 0, stream>>>(W4, Wih, Whh, y2);  // y2 dead; A4 ready
  k_final64<<<NT64, 256, 0, stream>>>(y3, w4t, wihh, whhh, edge, hidden,
                                      bias, bih, bhh, out);
}